// Round 19
// baseline (96.239 us; speedup 1.0000x reference)
//
#include <hip/hip_runtime.h>

namespace {
constexpr int Wd = 160, Hd = 192, Dd = 160, Bd = 2;
constexpr int HW = Hd * Wd;
constexpr int THREADS = 384;               // 6 waves: 2 producer + 4 consumer
constexpr int PTHREADS = 128;              // producer threads
constexpr int ROWS_OUT = 6;
constexpr int ROWS_LDS = 8;                // staged rows incl. h-halo
constexpr int RS = 164;                    // LDS row stride (floats)
constexpr int STRIPS = 40;
constexpr int COUTS = ROWS_OUT * STRIPS;   // 240 consumer outputs
constexpr int TASKS = 2 * ROWS_LDS * STRIPS;  // 640 = 5 * 128 exactly
constexpr int PTASKS = TASKS / PTHREADS;   // 5 tasks per producer thread
constexpr int BUFSTRIDE = 2 * ROWS_LDS * RS;  // floats between double buffers
constexpr int DCHUNK = 10;
constexpr int NCHUNK = Dd / DCHUNK;        // 16
constexpr int RGROUPS = Hd / ROWS_OUT;     // 32 -> grid 1024 = 4 blocks/CU
constexpr float EPS = 1e-8f;
}

using v4f = __attribute__((ext_vector_type(4))) float;

__device__ __forceinline__ float dpp_up1(float v) {   // lane i <- lane i-1
  return __int_as_float(__builtin_amdgcn_update_dpp(
      0, __float_as_int(v), 0x138, 0xF, 0xF, true));  // wave_shr:1
}
__device__ __forceinline__ float dpp_dn1(float v) {   // lane i <- lane i+1
  return __int_as_float(__builtin_amdgcn_update_dpp(
      0, __float_as_int(v), 0x130, 0xF, 0xF, true));  // wave_shl:1
}

__global__ __launch_bounds__(THREADS) void sobel_loss_kernel(
    const float* __restrict__ pred, const float* __restrict__ targ,
    float* __restrict__ out) {
  // double-buffered separable row partials: [buf][tensor][row][RS]
  __shared__ float lsw[2][2][ROWS_LDS][RS];   // 10.5 KB
  __shared__ float ldw[2][2][ROWS_LDS][RS];   // 10.5 KB
  const int tid = threadIdx.x;
  const int lane = tid & 63;
  const bool is_p = (tid < PTHREADS);         // waves 0-1: producers
  const int h0 = blockIdx.x * ROWS_OUT;
  const int d0 = blockIdx.y * DCHUNK;
  const size_t volOff = (size_t)blockIdx.z * Dd * HW;
  const float* pb = pred + volOff;
  const float* tb = targ + volOff;

  // ---- producer decode: 5 tasks/thread, covers all 640 tasks exactly ----
  const float* gs[PTASKS];
  float* psw[PTASKS];
  float* pdw[PTASKS];
  bool rok[PTASKS], zL[PTASKS], zR[PTASKS], pL[PTASKS], pR[PTASKS];
  float4 m[PTASKS];
  float hl[PTASKS], hr[PTASKS];
  if (is_p) {
#pragma unroll
    for (int u = 0; u < PTASKS; ++u) {
      const int i = tid + PTHREADS * u;        // 0..639
      const int t_ = i / (ROWS_LDS * STRIPS);
      const int rem = i - t_ * (ROWS_LDS * STRIPS);
      const int r8 = rem / STRIPS, s = rem - r8 * STRIPS;
      const int hh = h0 - 1 + r8;
      rok[u] = ((unsigned)hh < (unsigned)Hd);
      zL[u] = (s == 0);
      zR[u] = (s == STRIPS - 1);
      pL[u] = (lane == 0) && (s != 0);
      pR[u] = (lane == 63) && (s != STRIPS - 1);
      gs[u] = (t_ ? tb : pb) + (size_t)(rok[u] ? hh : 0) * Wd + s * 4;
      psw[u] = &lsw[0][t_][r8][s * 4];
      pdw[u] = &ldw[0][t_][r8][s * 4];
    }
  }

  auto GLOAD = [&](int d) {   // float4-only + <=2 exec-masked scalars per wave
    const bool dok = (unsigned)d < (unsigned)Dd;
    const size_t so = (size_t)d * HW;
#pragma unroll
    for (int u = 0; u < PTASKS; ++u) {
      float4 v = make_float4(0.f, 0.f, 0.f, 0.f);
      float a = 0.f, b = 0.f;
      if (dok && rok[u]) {
        v = *reinterpret_cast<const float4*>(gs[u] + so);
        if (pL[u]) a = gs[u][so - 1];
        if (pR[u]) b = gs[u][so + 4];
      }
      m[u] = v; hl[u] = a; hr[u] = b;
    }
  };

  auto STAGE = [&](int b) {   // w-conv once per staged row, write to buf b
#pragma unroll
    for (int u = 0; u < PTASKS; ++u) {
      float xl = dpp_up1(m[u].w);
      float xr = dpp_dn1(m[u].x);
      if (zL[u]) xl = 0.f;
      if (pL[u]) xl = hl[u];
      if (zR[u]) xr = 0.f;
      if (pR[u]) xr = hr[u];
      const float x0 = xl, x1 = m[u].x, x2 = m[u].y, x3 = m[u].z,
                  x4 = m[u].w, x5 = xr;
      float4 swv, dwv;
      swv.x = fmaf(2.f, x1, x0 + x2);  dwv.x = x2 - x0;
      swv.y = fmaf(2.f, x2, x1 + x3);  dwv.y = x3 - x1;
      swv.z = fmaf(2.f, x3, x2 + x4);  dwv.z = x4 - x2;
      swv.w = fmaf(2.f, x4, x3 + x5);  dwv.w = x5 - x3;
      *reinterpret_cast<float4*>(psw[u] + b * BUFSTRIDE) = swv;
      *reinterpret_cast<float4*>(pdw[u] + b * BUFSTRIDE) = dwv;
    }
  };

  // ---- consumer decode: waves 2-5, 240 of 256 threads active ----
  const int ctid = tid - PTHREADS;
  const int cr = ctid / STRIPS;
  const int cs4 = (ctid - cr * STRIPS) * 4;
  const bool is_c = (!is_p) && (ctid < COUTS);

  // rolling state [slot][tensor] as 4-wide vectors -> v_pk_* math
  v4f A[3][2], B[3][2], C[3][2];

  auto HCONV = [&](int slot, int b) {
#pragma unroll
    for (int t_ = 0; t_ < 2; ++t_) {
      const v4f sm = *reinterpret_cast<const v4f*>(&lsw[b][t_][cr][cs4]);
      const v4f s0 = *reinterpret_cast<const v4f*>(&lsw[b][t_][cr + 1][cs4]);
      const v4f sp = *reinterpret_cast<const v4f*>(&lsw[b][t_][cr + 2][cs4]);
      const v4f dm = *reinterpret_cast<const v4f*>(&ldw[b][t_][cr][cs4]);
      const v4f dd = *reinterpret_cast<const v4f*>(&ldw[b][t_][cr + 1][cs4]);
      const v4f dp = *reinterpret_cast<const v4f*>(&ldw[b][t_][cr + 2][cs4]);
      A[slot][t_] = s0 * 2.f + (sm + sp);
      B[slot][t_] = dd * 2.f + (dm + dp);
      C[slot][t_] = sp - sm;
    }
  };

  v4f accv = {0.f, 0.f, 0.f, 0.f};

  // ---- prologue: producers fill buf0 with slice d0-1, issue loads for d0 ----
  if (is_p) {
    GLOAD(d0 - 1);
    STAGE(0);                 // buf0 <- slice d0-1
    GLOAD(d0);                // regs <- slice d0 (consumed next iteration)
  }
  __syncthreads();

  // ---- main: iteration j handles slice m = d0-1+j (in buf[j&1]).
  //      producers: stage slice m+1 -> buf[(j+1)&1], load slice m+2.
  //      consumers: absorb slice m into slot j%3; emit slice m-1 when j>=2.
  //      ONE barrier per slice. ----
#pragma unroll
  for (int j = 0; j < DCHUNK + 2; ++j) {
    if (is_p) {
      if (j < DCHUNK + 1) STAGE((j + 1) & 1);       // buf <- slice d0+j
      if (j < DCHUNK) GLOAD(d0 + 1 + j);            // regs <- slice d0+1+j
    }
    if (is_c) {
      HCONV(j % 3, j & 1);                          // absorb slice d0-1+j
      if (j >= 2) {
        const int i0 = (j + 1) % 3, i1 = (j + 2) % 3, i2 = j % 3;
        const v4f gx0 = B[i1][0] * 2.f + (B[i0][0] + B[i2][0]);
        const v4f gy0 = C[i1][0] * 2.f + (C[i0][0] + C[i2][0]);
        const v4f gz0 = A[i2][0] - A[i0][0];
        const v4f q0 = gx0 * gx0 + gy0 * gy0 + gz0 * gz0 + EPS;
        const v4f gx1 = B[i1][1] * 2.f + (B[i0][1] + B[i2][1]);
        const v4f gy1 = C[i1][1] * 2.f + (C[i0][1] + C[i2][1]);
        const v4f gz1 = A[i2][1] - A[i0][1];
        const v4f q1 = gx1 * gx1 + gy1 * gy1 + gz1 * gz1 + EPS;
        v4f dd_;
#pragma unroll
        for (int jj = 0; jj < 4; ++jj)
          dd_[jj] = __builtin_amdgcn_sqrtf(q0[jj]) -
                    __builtin_amdgcn_sqrtf(q1[jj]);
#pragma unroll
        for (int jj = 0; jj < 4; ++jj) dd_[jj] = fabsf(dd_[jj]);
        accv += dd_;
      }
    }
    __syncthreads();
  }

  // ---- reduction: wave shfl -> LDS -> one atomic per block ----
  float sred = accv.x + accv.y + accv.z + accv.w;
#pragma unroll
  for (int off = 32; off > 0; off >>= 1) sred += __shfl_down(sred, off, 64);
  __shared__ float wsum[THREADS / 64];
  const int wid = tid >> 6;
  if (lane == 0) wsum[wid] = sred;
  __syncthreads();
  if (tid == 0) {
    float t = 0.f;
#pragma unroll
    for (int i = 0; i < THREADS / 64; ++i) t += wsum[i];
    atomicAdd(out, t * (1.0f / (float)((size_t)Bd * Dd * Hd * Wd)));
  }
}

extern "C" void kernel_launch(void* const* d_in, const int* in_sizes, int n_in,
                              void* d_out, int out_size, void* d_ws, size_t ws_size,
                              hipStream_t stream) {
  const float* pred = (const float*)d_in[0];
  const float* targ = (const float*)d_in[1];
  float* out = (float*)d_out;
  (void)in_sizes; (void)n_in; (void)out_size; (void)d_ws; (void)ws_size;

  hipMemsetAsync(out, 0, sizeof(float), stream);
  dim3 grid(RGROUPS, NCHUNK, Bd);
  sobel_loss_kernel<<<grid, THREADS, 0, stream>>>(pred, targ, out);
}

// Round 20
// 35.530 us; speedup vs baseline: 2.7086x; 2.7086x over previous
//
#include <hip/hip_runtime.h>

namespace {
constexpr int Wd = 160, Hd = 192, Dd = 160, Bd = 2;
constexpr int HW = Hd * Wd;
constexpr int THREADS = 256;               // 4 waves
constexpr int ROWS_OUT = 6;                // output rows per block
constexpr int ROWS_LDS = 8;                // staged rows incl. h-halo
constexpr int RS = 164;                    // LDS row stride (in halves)
constexpr int STRIPS = 40;                 // 4-wide strips per row
constexpr int CTHREADS = ROWS_OUT * STRIPS;   // 240 compute threads
constexpr int TASKS = 2 * ROWS_LDS * STRIPS;  // 640 staging tasks
constexpr int DCHUNK = 10;                 // grid 1024 (proven best)
constexpr int NCHUNK = Dd / DCHUNK;        // 16
constexpr int RGROUPS = Hd / ROWS_OUT;     // 32
constexpr float EPS = 1e-8f;
}

using v4f = __attribute__((ext_vector_type(4))) float;
using v4h = __attribute__((ext_vector_type(4))) _Float16;

__device__ __forceinline__ float dpp_up1(float v) {   // lane i <- lane i-1
  return __int_as_float(__builtin_amdgcn_update_dpp(
      0, __float_as_int(v), 0x138, 0xF, 0xF, true));  // wave_shr:1
}
__device__ __forceinline__ float dpp_dn1(float v) {   // lane i <- lane i+1
  return __int_as_float(__builtin_amdgcn_update_dpp(
      0, __float_as_int(v), 0x130, 0xF, 0xF, true));  // wave_shl:1
}

__global__ __launch_bounds__(THREADS) void sobel_loss_kernel(
    const float* __restrict__ pred, const float* __restrict__ targ,
    float* __restrict__ out) {
  // staged separable row partials in fp16: sw = [1,2,1]_w*x, dw = [-1,0,1]_w*x
  __shared__ __align__(16) _Float16 lsw[2][ROWS_LDS][RS];   // 5.2 KB
  __shared__ __align__(16) _Float16 ldw[2][ROWS_LDS][RS];   // 5.2 KB
  const int tid = threadIdx.x;
  const int lane = tid & 63;
  const int h0 = blockIdx.x * ROWS_OUT;
  const int d0 = blockIdx.y * DCHUNK;
  const size_t volOff = (size_t)blockIdx.z * Dd * HW;
  const float* pb = pred + volOff;
  const float* tb = targ + volOff;

  // ---- staging task decode (2.5 tasks/thread, loop-invariant) ----
  const float* gs[3];
  _Float16* psw[3];
  _Float16* pdw[3];
  bool sok[3], rok[3], zL[3], zR[3], pL[3], pR[3];
#pragma unroll
  for (int u = 0; u < 3; ++u) {
    const int i = tid + 256 * u;
    const bool ok = (i < TASKS);
    const int ic = ok ? i : 0;
    const int t_ = ic / (ROWS_LDS * STRIPS);
    const int rem = ic - t_ * (ROWS_LDS * STRIPS);
    const int r8 = rem / STRIPS, s = rem - r8 * STRIPS;
    const int hh = h0 - 1 + r8;
    const bool rv = ok && ((unsigned)hh < (unsigned)Hd);
    sok[u] = ok;
    rok[u] = rv;
    zL[u] = (s == 0);
    zR[u] = (s == STRIPS - 1);
    pL[u] = ok && (lane == 0) && (s != 0);
    pR[u] = ok && (lane == 63) && (s != STRIPS - 1);
    gs[u] = (t_ ? tb : pb) + (size_t)(rv ? hh : 0) * Wd + s * 4;
    psw[u] = &lsw[t_][r8][s * 4];
    pdw[u] = &ldw[t_][r8][s * 4];
  }

  float4 m[3];
  float hl[3], hr[3];
  auto GLOAD = [&](int d) {   // float4-only + <=2 exec-masked scalars per wave
    const bool dok = (unsigned)d < (unsigned)Dd;
    const size_t so = (size_t)d * HW;
#pragma unroll
    for (int u = 0; u < 3; ++u) {
      float4 v = make_float4(0.f, 0.f, 0.f, 0.f);
      float a = 0.f, b = 0.f;
      if (dok && rok[u]) {
        v = *reinterpret_cast<const float4*>(gs[u] + so);
        if (pL[u]) a = gs[u][so - 1];
        if (pR[u]) b = gs[u][so + 4];
      }
      m[u] = v; hl[u] = a; hr[u] = b;
    }
  };

  auto STAGE = [&]() {   // w-conv in f32, convert, write fp16 sw/dw (b64)
#pragma unroll
    for (int u = 0; u < 3; ++u) {
      float xl = dpp_up1(m[u].w);          // lane-1 holds x[4s-4..4s-1]
      float xr = dpp_dn1(m[u].x);          // lane+1 holds x[4s+4..4s+7]
      if (zL[u]) xl = 0.f;
      if (pL[u]) xl = hl[u];
      if (zR[u]) xr = 0.f;
      if (pR[u]) xr = hr[u];
      const float x0 = xl, x1 = m[u].x, x2 = m[u].y, x3 = m[u].z,
                  x4 = m[u].w, x5 = xr;
      v4f swf, dwf;
      swf[0] = fmaf(2.f, x1, x0 + x2);  dwf[0] = x2 - x0;
      swf[1] = fmaf(2.f, x2, x1 + x3);  dwf[1] = x3 - x1;
      swf[2] = fmaf(2.f, x3, x2 + x4);  dwf[2] = x4 - x2;
      swf[3] = fmaf(2.f, x4, x3 + x5);  dwf[3] = x5 - x3;
      if (sok[u]) {
        *reinterpret_cast<v4h*>(psw[u]) = __builtin_convertvector(swf, v4h);
        *reinterpret_cast<v4h*>(pdw[u]) = __builtin_convertvector(dwf, v4h);
      }
    }
  };

  // ---- compute decode: output row cr (0..5), strip cs (0..39) ----
  const int cr = tid / STRIPS;
  const int cs4 = (tid - cr * STRIPS) * 4;
  const bool is_c = (tid < CTHREADS);

  // rolling state [slot][tensor] as packed fp16 -> v_pk_*_f16 math
  v4h A[3][2], B[3][2], C[3][2];
  const _Float16 h2 = (_Float16)2.0f;

  auto HCONV = [&](int slot) {
#pragma unroll
    for (int t_ = 0; t_ < 2; ++t_) {
      const v4h sm = *reinterpret_cast<const v4h*>(&lsw[t_][cr][cs4]);
      const v4h s0 = *reinterpret_cast<const v4h*>(&lsw[t_][cr + 1][cs4]);
      const v4h sp = *reinterpret_cast<const v4h*>(&lsw[t_][cr + 2][cs4]);
      const v4h dm = *reinterpret_cast<const v4h*>(&ldw[t_][cr][cs4]);
      const v4h dd = *reinterpret_cast<const v4h*>(&ldw[t_][cr + 1][cs4]);
      const v4h dp = *reinterpret_cast<const v4h*>(&ldw[t_][cr + 2][cs4]);
      A[slot][t_] = s0 * h2 + (sm + sp);
      B[slot][t_] = dd * h2 + (dm + dp);
      C[slot][t_] = sp - sm;
    }
  };

  v4f accv = {0.f, 0.f, 0.f, 0.f};

  // ---- prologue: slices d0-1 (slot0) and d0 (slot1) ----
  GLOAD(d0 - 1);
  STAGE(); GLOAD(d0); __syncthreads();
  if (is_c) HCONV(0);
  __syncthreads();
  STAGE(); GLOAD(d0 + 1); __syncthreads();
  if (is_c) HCONV(1);
  __syncthreads();

  // ---- main loop, fully unrolled: output slice d0+k ----
#pragma unroll
  for (int k = 0; k < DCHUNK; ++k) {
    STAGE();                               // LDS <- slice d0+1+k (loaded last iter)
    if (k < DCHUNK - 1) GLOAD(d0 + 2 + k); // issue next; consumed next iter top
    __syncthreads();
    const int i0 = k % 3, i1 = (k + 1) % 3, i2 = (k + 2) % 3;
    if (is_c) {
      HCONV(i2);                           // state <- slice d0+1+k
      const v4h gx0 = B[i1][0] * h2 + (B[i0][0] + B[i2][0]);
      const v4h gy0 = C[i1][0] * h2 + (C[i0][0] + C[i2][0]);
      const v4h gz0 = A[i2][0] - A[i0][0];
      const v4h q0h = gx0 * gx0 + gy0 * gy0 + gz0 * gz0;
      const v4h gx1 = B[i1][1] * h2 + (B[i0][1] + B[i2][1]);
      const v4h gy1 = C[i1][1] * h2 + (C[i0][1] + C[i2][1]);
      const v4h gz1 = A[i2][1] - A[i0][1];
      const v4h q1h = gx1 * gx1 + gy1 * gy1 + gz1 * gz1;
      const v4f q0 = __builtin_convertvector(q0h, v4f) + EPS;
      const v4f q1 = __builtin_convertvector(q1h, v4f) + EPS;
      v4f dd_;
#pragma unroll
      for (int j = 0; j < 4; ++j)
        dd_[j] = __builtin_amdgcn_sqrtf(q0[j]) - __builtin_amdgcn_sqrtf(q1[j]);
#pragma unroll
      for (int j = 0; j < 4; ++j) dd_[j] = fabsf(dd_[j]);
      accv += dd_;
    }
    __syncthreads();
  }

  // ---- reduction: wave shfl -> LDS -> one atomic per block ----
  float sred = accv[0] + accv[1] + accv[2] + accv[3];
#pragma unroll
  for (int off = 32; off > 0; off >>= 1) sred += __shfl_down(sred, off, 64);
  __shared__ float wsum[THREADS / 64];
  const int wid = tid >> 6;
  if (lane == 0) wsum[wid] = sred;
  __syncthreads();
  if (tid == 0) {
    float t = 0.f;
#pragma unroll
    for (int i = 0; i < THREADS / 64; ++i) t += wsum[i];
    atomicAdd(out, t * (1.0f / (float)((size_t)Bd * Dd * Hd * Wd)));
  }
}

extern "C" void kernel_launch(void* const* d_in, const int* in_sizes, int n_in,
                              void* d_out, int out_size, void* d_ws, size_t ws_size,
                              hipStream_t stream) {
  const float* pred = (const float*)d_in[0];
  const float* targ = (const float*)d_in[1];
  float* out = (float*)d_out;
  (void)in_sizes; (void)n_in; (void)out_size; (void)d_ws; (void)ws_size;

  hipMemsetAsync(out, 0, sizeof(float), stream);
  dim3 grid(RGROUPS, NCHUNK, Bd);
  sobel_loss_kernel<<<grid, THREADS, 0, stream>>>(pred, targ, out);
}